// Round 1
// baseline (314.486 us; speedup 1.0000x reference)
//
#include <hip/hip_runtime.h>

// Boundary_binaryLoss: 15x15 binary morphology boundary mask + masked NLL mean.
// B=32, C=2, H=480, W=864. logits [B,C,H,W] f32, labels [B,H,W] i32 in {0,1,255}.
//
// valid(b,h,w) = (label != 255) && (clipped 15x15 window contains a pixel with
//   np_label==0 (label 0 or 255) AND a pixel with np_label==255 (label 1))
// loss = -sum(valid ? logits[b,label,h,w] : 0) / max(#valid, 1)
//
// Design: per-block 64x32 output tile, halo-staged label flag bytes in LDS
// (80-byte rows, 4-aligned so the left halo of -7 fits at byte offset +1 of a
// dword grid; W%4==0 means halo words are never partially in-bounds).
// Horizontal 15-OR: 4 output cols per thread from 5 aligned LDS dwords via
// byte-fold SWAR. Vertical 15-OR: plain dword ORs. Gather: float4 loads of
// both channels + per-byte select. Double accumulation + 1 fp64 atomic/block.

namespace {
constexpr int B_ = 32;
constexpr int H_ = 480;
constexpr int W_ = 864;
constexpr int TW = 64;
constexpr int TH = 32;
constexpr int R_ = 7;
constexpr int LH = TH + 2 * R_;   // 46 halo rows
constexpr int WC = 20;            // 80 halo bytes per row, as dwords
constexpr int HC = TW / 4;        // 16 output dwords per row
} // namespace

__device__ __forceinline__ unsigned fold4(unsigned x) {
  // OR the four bytes of x into the low byte
  x |= x >> 16;
  x |= x >> 8;
  return x & 0xFFu;
}

__device__ __forceinline__ unsigned flag_of(int v) {
  // np_label = (v==255) ? 0 : v*255
  // bit0: np_label==0  (v==0 || v==255)   -> feeds erosion-min==0
  // bit1: np_label==255 (v==1)            -> feeds dilation-max==255
  return (v == 0 || v == 255) ? 1u : (v == 1 ? 2u : 0u);
}

extern "C" __global__ __launch_bounds__(256, 4)
void boundary_loss_main(const float* __restrict__ logits,
                        const int* __restrict__ labels,
                        double* __restrict__ gsum,
                        unsigned long long* __restrict__ gcnt)
{
  __shared__ unsigned sflag[LH][WC];  // per-byte window flags
  __shared__ unsigned sraw[LH][WC];   // raw label bytes (center lookup)
  __shared__ unsigned hfl[LH][WC ? HC : HC];  // horizontal 15-OR result
  __shared__ double red_s[4];
  __shared__ unsigned red_c[4];

  const int tid = threadIdx.x;
  const int tile_w = blockIdx.x * TW;
  const int tile_h = blockIdx.y * TH;
  const int b = blockIdx.z;

  const int* __restrict__ lab = labels + (size_t)b * H_ * W_;

  // ---- stage halo labels into LDS: raw bytes + flag bytes ----
  // halo covers global cols [tile_w-8, tile_w+72): dword-aligned, W%4==0 so
  // every halo dword is either fully in-bounds or fully out.
  for (int it = tid; it < LH * WC; it += 256) {
    const int r = it / WC;
    const int wc = it - r * WC;
    const int gh = tile_h - R_ + r;
    const int gw = tile_w - 8 + wc * 4;
    unsigned raw = 0xC8C8C8C8u;  // OOB marker (never matches 0/1/255)
    unsigned flg = 0u;           // OOB contributes to neither min nor max
    if (gh >= 0 && gh < H_ && gw >= 0 && gw < W_) {
      const int4 v = *(const int4*)(lab + (size_t)gh * W_ + gw);
      raw = (unsigned)(v.x & 0xFF) | ((unsigned)(v.y & 0xFF) << 8) |
            ((unsigned)(v.z & 0xFF) << 16) | ((unsigned)(v.w & 0xFF) << 24);
      flg = flag_of(v.x) | (flag_of(v.y) << 8) | (flag_of(v.z) << 16) |
            (flag_of(v.w) << 24);
    }
    sraw[r][wc] = raw;
    sflag[r][wc] = flg;
  }
  __syncthreads();

  // ---- horizontal 15-wide OR, 4 output columns per item ----
  // output col c (tile coords, c=wc*4) windows cover halo bytes cc in
  // [c+1, c+15] .. [c+4, c+18]  -> dwords wc..wc+4
  for (int it = tid; it < LH * HC; it += 256) {
    const int r = it >> 4;
    const int wc = it & 15;
    const unsigned w0 = sflag[r][wc];
    const unsigned w1 = sflag[r][wc + 1];
    const unsigned w2 = sflag[r][wc + 2];
    const unsigned w3 = sflag[r][wc + 3];
    const unsigned w4 = sflag[r][wc + 4];
    const unsigned core = fold4(w1 | w2 | w3);
    const unsigned o0 = core | fold4(w0 >> 8);                    // cc c+1..c+15
    const unsigned o1 = core | fold4(w0 >> 16) | (w4 & 0xFFu);    // cc c+2..c+16
    const unsigned o2 = core | (w0 >> 24) | fold4(w4 & 0xFFFFu);  // cc c+3..c+17
    const unsigned o3 = core | fold4(w4 & 0xFFFFFFu);             // cc c+4..c+18
    hfl[r][wc] = o0 | (o1 << 8) | (o2 << 16) | (o3 << 24);
  }
  __syncthreads();

  // ---- vertical 15-tall OR + gather + accumulate ----
  double lsum = 0.0;
  unsigned lcnt = 0;
  const float* __restrict__ lg0 = logits + (size_t)b * 2 * H_ * W_;
  const float* __restrict__ lg1 = lg0 + (size_t)H_ * W_;

  for (int it = tid; it < TH * HC; it += 256) {
    const int r = it >> 4;
    const int wc = it & 15;
    const int gw0 = tile_w + wc * 4;
    if (gw0 < W_) {
      unsigned acc = 0;
#pragma unroll
      for (int k = 0; k < 15; ++k) acc |= hfl[r + k][wc];
      const unsigned craw = sraw[r + R_][wc + 2];  // center labels, byte j
      const int gh = tile_h + r;
      const size_t off = (size_t)gh * W_ + gw0;
      const float4 v0 = *(const float4*)(lg0 + off);
      const float4 v1 = *(const float4*)(lg1 + off);
      const float c0[4] = {v0.x, v0.y, v0.z, v0.w};
      const float c1[4] = {v1.x, v1.y, v1.z, v1.w};
#pragma unroll
      for (int j = 0; j < 4; ++j) {
        const unsigned fb = (acc >> (8 * j)) & 0xFFu;
        const unsigned lv = (craw >> (8 * j)) & 0xFFu;
        if (fb == 3u && lv != 255u) {
          lsum += (double)(lv ? c1[j] : c0[j]);
          ++lcnt;
        }
      }
    }
  }

  // ---- block reduction: wave shuffles -> LDS -> one atomic pair ----
#pragma unroll
  for (int off = 32; off > 0; off >>= 1) {
    lsum += __shfl_down(lsum, off, 64);
    lcnt += __shfl_down(lcnt, off, 64);
  }
  const int wave = tid >> 6;
  if ((tid & 63) == 0) { red_s[wave] = lsum; red_c[wave] = lcnt; }
  __syncthreads();
  if (tid == 0) {
    const double s = red_s[0] + red_s[1] + red_s[2] + red_s[3];
    const unsigned c = red_c[0] + red_c[1] + red_c[2] + red_c[3];
    atomicAdd(gsum, s);
    atomicAdd(gcnt, (unsigned long long)c);
  }
}

extern "C" __global__ void boundary_loss_final(const double* __restrict__ gsum,
                                               const unsigned long long* __restrict__ gcnt,
                                               float* __restrict__ out)
{
  if (threadIdx.x == 0 && blockIdx.x == 0) {
    unsigned long long c = *gcnt;
    if (c == 0ull) c = 1ull;
    out[0] = (float)(-(*gsum) / (double)c);
  }
}

extern "C" void kernel_launch(void* const* d_in, const int* in_sizes, int n_in,
                              void* d_out, int out_size, void* d_ws, size_t ws_size,
                              hipStream_t stream)
{
  const float* logits = (const float*)d_in[0];
  const int* labels = (const int*)d_in[1];
  float* out = (float*)d_out;
  double* gsum = (double*)d_ws;
  unsigned long long* gcnt = (unsigned long long*)((char*)d_ws + 8);

  // harness poisons d_ws with 0xAA before every timed launch
  hipMemsetAsync(d_ws, 0, 16, stream);

  dim3 grid((W_ + TW - 1) / TW, H_ / TH, B_);
  boundary_loss_main<<<grid, 256, 0, stream>>>(logits, labels, gsum, gcnt);
  boundary_loss_final<<<1, 64, 0, stream>>>(gsum, gcnt, out);
}

// Round 2
// 195.348 us; speedup vs baseline: 1.6099x; 1.6099x over previous
//
#include <hip/hip_runtime.h>

// Boundary_binaryLoss: 15x15 binary morphology boundary mask + masked NLL mean.
// B=32, C=2, H=480, W=864. logits [B,C,H,W] f32, labels [B,H,W] i32 in {0,1,255}.
//
// valid(b,h,w) = (label != 255) && (clipped 15x15 window contains a pixel with
//   np_label==0 (label 0 or 255) AND a pixel with np_label==255 (label 1))
// loss = -sum(valid ? logits[b,label,h,w] : 0) / max(#valid, 1)
//
// R1 lesson: 6720 blocks x 2 same-cache-line device atomics serialized at L2
// (~13 ns each) -> 180 us kernel + 134 us drain gap. This version writes one
// double2 partial per block to d_ws (every slot written -> no init needed,
// harness 0xAA poison harmless) and reduces in a single 1024-thread block.

namespace {
constexpr int B_ = 32;
constexpr int H_ = 480;
constexpr int W_ = 864;
constexpr int TW = 64;
constexpr int TH = 32;
constexpr int R_ = 7;
constexpr int LH = TH + 2 * R_;   // 46 halo rows
constexpr int WC = 20;            // 80 halo bytes per row, as dwords
constexpr int HC = TW / 4;        // 16 output dwords per row
constexpr int GX = (W_ + TW - 1) / TW;  // 14
constexpr int GY = H_ / TH;             // 15
constexpr int NBLK = GX * GY * B_;      // 6720
} // namespace

__device__ __forceinline__ unsigned fold4(unsigned x) {
  x |= x >> 16;
  x |= x >> 8;
  return x & 0xFFu;
}

__device__ __forceinline__ unsigned flag_of(int v) {
  // np_label = (v==255) ? 0 : v*255
  // bit0: np_label==0  (v==0 || v==255), bit1: np_label==255 (v==1)
  return (v == 0 || v == 255) ? 1u : (v == 1 ? 2u : 0u);
}

extern "C" __global__ __launch_bounds__(256, 4)
void boundary_loss_main(const float* __restrict__ logits,
                        const int* __restrict__ labels,
                        double2* __restrict__ partials)
{
  __shared__ unsigned sflag[LH][WC];  // per-byte window flags
  __shared__ unsigned sraw[LH][WC];   // raw label bytes (center lookup)
  __shared__ unsigned hfl[LH][HC];    // horizontal 15-OR result
  __shared__ double red_s[4];
  __shared__ unsigned red_c[4];

  const int tid = threadIdx.x;
  const int tile_w = blockIdx.x * TW;
  const int tile_h = blockIdx.y * TH;
  const int b = blockIdx.z;

  const int* __restrict__ lab = labels + (size_t)b * H_ * W_;

  // ---- stage halo labels into LDS: raw bytes + flag bytes ----
  // halo cols [tile_w-8, tile_w+72): dword-aligned; W%4==0 so each halo dword
  // is fully in-bounds or fully out.
  for (int it = tid; it < LH * WC; it += 256) {
    const int r = it / WC;
    const int wc = it - r * WC;
    const int gh = tile_h - R_ + r;
    const int gw = tile_w - 8 + wc * 4;
    unsigned raw = 0xC8C8C8C8u;  // OOB marker (never matches 0/1/255)
    unsigned flg = 0u;           // OOB contributes to neither min nor max
    if (gh >= 0 && gh < H_ && gw >= 0 && gw < W_) {
      const int4 v = *(const int4*)(lab + (size_t)gh * W_ + gw);
      raw = (unsigned)(v.x & 0xFF) | ((unsigned)(v.y & 0xFF) << 8) |
            ((unsigned)(v.z & 0xFF) << 16) | ((unsigned)(v.w & 0xFF) << 24);
      flg = flag_of(v.x) | (flag_of(v.y) << 8) | (flag_of(v.z) << 16) |
            (flag_of(v.w) << 24);
    }
    sraw[r][wc] = raw;
    sflag[r][wc] = flg;
  }
  __syncthreads();

  // ---- horizontal 15-wide OR, 4 output columns per item ----
  for (int it = tid; it < LH * HC; it += 256) {
    const int r = it >> 4;
    const int wc = it & 15;
    const unsigned w0 = sflag[r][wc];
    const unsigned w1 = sflag[r][wc + 1];
    const unsigned w2 = sflag[r][wc + 2];
    const unsigned w3 = sflag[r][wc + 3];
    const unsigned w4 = sflag[r][wc + 4];
    const unsigned core = fold4(w1 | w2 | w3);
    const unsigned o0 = core | fold4(w0 >> 8);                    // c+1..c+15
    const unsigned o1 = core | fold4(w0 >> 16) | (w4 & 0xFFu);    // c+2..c+16
    const unsigned o2 = core | (w0 >> 24) | fold4(w4 & 0xFFFFu);  // c+3..c+17
    const unsigned o3 = core | fold4(w4 & 0xFFFFFFu);             // c+4..c+18
    hfl[r][wc] = o0 | (o1 << 8) | (o2 << 16) | (o3 << 24);
  }
  __syncthreads();

  // ---- vertical 15-tall OR + gather + accumulate ----
  double lsum = 0.0;
  unsigned lcnt = 0;
  const float* __restrict__ lg0 = logits + (size_t)b * 2 * H_ * W_;
  const float* __restrict__ lg1 = lg0 + (size_t)H_ * W_;

  for (int it = tid; it < TH * HC; it += 256) {
    const int r = it >> 4;
    const int wc = it & 15;
    const int gw0 = tile_w + wc * 4;
    if (gw0 < W_) {
      unsigned acc = 0;
#pragma unroll
      for (int k = 0; k < 15; ++k) acc |= hfl[r + k][wc];
      const unsigned craw = sraw[r + R_][wc + 2];  // center labels
      const int gh = tile_h + r;
      const size_t off = (size_t)gh * W_ + gw0;
      const float4 v0 = *(const float4*)(lg0 + off);
      const float4 v1 = *(const float4*)(lg1 + off);
      const float c0[4] = {v0.x, v0.y, v0.z, v0.w};
      const float c1[4] = {v1.x, v1.y, v1.z, v1.w};
#pragma unroll
      for (int j = 0; j < 4; ++j) {
        const unsigned fb = (acc >> (8 * j)) & 0xFFu;
        const unsigned lv = (craw >> (8 * j)) & 0xFFu;
        if (fb == 3u && lv != 255u) {
          lsum += (double)(lv ? c1[j] : c0[j]);
          ++lcnt;
        }
      }
    }
  }

  // ---- block reduction -> ONE double2 store per block (no atomics) ----
#pragma unroll
  for (int off = 32; off > 0; off >>= 1) {
    lsum += __shfl_down(lsum, off, 64);
    lcnt += __shfl_down(lcnt, off, 64);
  }
  const int wave = tid >> 6;
  if ((tid & 63) == 0) { red_s[wave] = lsum; red_c[wave] = lcnt; }
  __syncthreads();
  if (tid == 0) {
    const double s = red_s[0] + red_s[1] + red_s[2] + red_s[3];
    const double c = (double)(red_c[0] + red_c[1] + red_c[2] + red_c[3]);
    const int bid = (blockIdx.z * GY + blockIdx.y) * GX + blockIdx.x;
    partials[bid] = make_double2(s, c);
  }
}

extern "C" __global__ __launch_bounds__(1024)
void boundary_loss_final(const double2* __restrict__ partials,
                         float* __restrict__ out)
{
  __shared__ double red_s[16];
  __shared__ double red_c[16];
  const int tid = threadIdx.x;
  double s = 0.0, c = 0.0;
  for (int i = tid; i < NBLK; i += 1024) {
    const double2 p = partials[i];
    s += p.x;
    c += p.y;
  }
#pragma unroll
  for (int off = 32; off > 0; off >>= 1) {
    s += __shfl_down(s, off, 64);
    c += __shfl_down(c, off, 64);
  }
  const int wave = tid >> 6;
  if ((tid & 63) == 0) { red_s[wave] = s; red_c[wave] = c; }
  __syncthreads();
  if (tid == 0) {
    double ts = 0.0, tc = 0.0;
#pragma unroll
    for (int i = 0; i < 16; ++i) { ts += red_s[i]; tc += red_c[i]; }
    if (tc < 1.0) tc = 1.0;
    out[0] = (float)(-ts / tc);
  }
}

extern "C" void kernel_launch(void* const* d_in, const int* in_sizes, int n_in,
                              void* d_out, int out_size, void* d_ws, size_t ws_size,
                              hipStream_t stream)
{
  const float* logits = (const float*)d_in[0];
  const int* labels = (const int*)d_in[1];
  float* out = (float*)d_out;
  double2* partials = (double2*)d_ws;  // NBLK * 16 B = 107,520 B; every slot
                                       // written by main -> no init needed.

  dim3 grid(GX, GY, B_);
  boundary_loss_main<<<grid, 256, 0, stream>>>(logits, labels, partials);
  boundary_loss_final<<<1, 1024, 0, stream>>>(partials, out);
}

// Round 3
// 194.119 us; speedup vs baseline: 1.6201x; 1.0063x over previous
//
#include <hip/hip_runtime.h>

// Boundary_binaryLoss: 15x15 binary morphology boundary mask + masked NLL mean.
// B=32, C=2, H=480, W=864. logits [B,C,H,W] f32, labels [B,H,W] i32 in {0,1,255}.
//
// valid(b,h,w) = (label != 255) && (clipped 15x15 window contains a pixel with
//   np_label==0 (label 0 or 255) AND a pixel with np_label==255 (label 1))
// loss = -sum(valid ? logits[b,label,h,w] : 0) / max(#valid, 1)
//
// R1: same-line device atomics serialized (180us) -> per-block double2 partials.
// R2: block was a serial chain (labels->barrier->H-OR->barrier->logits gather),
//     logits latency fully exposed at block tail (64us, VALU 26%, HBM 25%).
//     Now ALL global loads (labels + logits) are issued into registers at
//     block start; the logits' ~900cy latency hides behind flag-pack + two
//     barriers + horizontal OR. __launch_bounds__(256,8) keeps VGPR<=64 so
//     the full 32 waves/CU stay resident.

namespace {
constexpr int B_ = 32;
constexpr int H_ = 480;
constexpr int W_ = 864;
constexpr int TW = 64;
constexpr int TH = 32;
constexpr int R_ = 7;
constexpr int LH = TH + 2 * R_;   // 46 halo rows
constexpr int WC = 20;            // 80 halo bytes per row, as dwords
constexpr int HC = TW / 4;        // 16 output dwords per row
constexpr int GX = (W_ + TW - 1) / TW;  // 14
constexpr int GY = H_ / TH;             // 15
constexpr int NBLK = GX * GY * B_;      // 6720
} // namespace

__device__ __forceinline__ unsigned fold4(unsigned x) {
  x |= x >> 16;
  x |= x >> 8;
  return x & 0xFFu;
}

__device__ __forceinline__ unsigned flag_of(int v) {
  // np_label = (v==255) ? 0 : v*255
  // bit0: np_label==0  (v==0 || v==255), bit1: np_label==255 (v==1)
  return (v == 0 || v == 255) ? 1u : (v == 1 ? 2u : 0u);
}

extern "C" __global__ __launch_bounds__(256, 8)
void boundary_loss_main(const float* __restrict__ logits,
                        const int* __restrict__ labels,
                        double2* __restrict__ partials)
{
  __shared__ unsigned sflag[LH][WC];  // per-byte window flags
  __shared__ unsigned sraw[LH][WC];   // raw label bytes (center lookup)
  __shared__ unsigned hfl[LH][HC];    // horizontal 15-OR result
  __shared__ double red_s[4];
  __shared__ unsigned red_c[4];

  const int tid = threadIdx.x;
  const int tile_w = blockIdx.x * TW;
  const int tile_h = blockIdx.y * TH;
  const int b = blockIdx.z;

  const int* __restrict__ lab = labels + (size_t)b * H_ * W_;
  const float* __restrict__ lg0 = logits + (size_t)b * 2 * H_ * W_;
  const float* __restrict__ lg1 = lg0 + (size_t)H_ * W_;

  // ================= issue ALL global loads up front =================
  // ---- label halo loads (needed first; feed phase 1) ----
  // halo cols [tile_w-8, tile_w+72): dword-aligned; W%4==0 so each halo dword
  // is fully in-bounds or fully out. LH*WC = 920 items, 4 rounds of 256.
  int4 lv[4];
#pragma unroll
  for (int u = 0; u < 4; ++u) {
    const int it = tid + 256 * u;
    const int r = it / WC;
    const int wcc = it - r * WC;
    const int gh = tile_h - R_ + r;
    const int gw = tile_w - 8 + wcc * 4;
    lv[u] = make_int4(200, 200, 200, 200);  // OOB: 0xC8 bytes, flag 0
    if (it < LH * WC && gh >= 0 && gh < H_ && gw >= 0 && gw < W_)
      lv[u] = *(const int4*)(lab + (size_t)gh * W_ + gw);
  }

  // ---- logits prefetch (consumed only after both barriers) ----
  // thread -> (row r0, dword-col wcp); item A row r0, item B row r0+16.
  const int r0 = tid >> 4;   // 0..15
  const int wcp = tid & 15;
  const int gw0 = tile_w + wcp * 4;
  const bool inb = gw0 < W_;  // last tile covers only cols 832..863
  float4 pA0 = make_float4(0, 0, 0, 0), pA1 = pA0, pB0 = pA0, pB1 = pA0;
  if (inb) {
    const size_t offA = (size_t)(tile_h + r0) * W_ + gw0;
    const size_t offB = offA + (size_t)16 * W_;
    pA0 = *(const float4*)(lg0 + offA);
    pA1 = *(const float4*)(lg1 + offA);
    pB0 = *(const float4*)(lg0 + offB);
    pB1 = *(const float4*)(lg1 + offB);
  }

  // ================= phase 1: pack labels -> LDS =================
#pragma unroll
  for (int u = 0; u < 4; ++u) {
    const int it = tid + 256 * u;
    if (it < LH * WC) {
      const int r = it / WC;
      const int wcc = it - r * WC;
      const int4 v = lv[u];
      const unsigned raw = (unsigned)(v.x & 0xFF) | ((unsigned)(v.y & 0xFF) << 8) |
                           ((unsigned)(v.z & 0xFF) << 16) | ((unsigned)(v.w & 0xFF) << 24);
      const unsigned flg = flag_of(v.x) | (flag_of(v.y) << 8) |
                           (flag_of(v.z) << 16) | (flag_of(v.w) << 24);
      sraw[r][wcc] = raw;
      sflag[r][wcc] = flg;
    }
  }
  __syncthreads();

  // ================= phase 2: horizontal 15-wide OR =================
  // output col c (tile coords, c=wc*4) windows cover halo bytes in dwords
  // wc..wc+4 of the 80-byte halo row.
  for (int it = tid; it < LH * HC; it += 256) {
    const int r = it >> 4;
    const int wc = it & 15;
    const unsigned w0 = sflag[r][wc];
    const unsigned w1 = sflag[r][wc + 1];
    const unsigned w2 = sflag[r][wc + 2];
    const unsigned w3 = sflag[r][wc + 3];
    const unsigned w4 = sflag[r][wc + 4];
    const unsigned core = fold4(w1 | w2 | w3);
    const unsigned o0 = core | fold4(w0 >> 8);                    // c+1..c+15
    const unsigned o1 = core | fold4(w0 >> 16) | (w4 & 0xFFu);    // c+2..c+16
    const unsigned o2 = core | (w0 >> 24) | fold4(w4 & 0xFFFFu);  // c+3..c+17
    const unsigned o3 = core | fold4(w4 & 0xFFFFFFu);             // c+4..c+18
    hfl[r][wc] = o0 | (o1 << 8) | (o2 << 16) | (o3 << 24);
  }
  __syncthreads();

  // ========== phase 3: vertical 15-OR + select prefetched logits ==========
  double lsum = 0.0;
  unsigned lcnt = 0;
  if (inb) {
    unsigned accA = 0, accB = 0;
#pragma unroll
    for (int k = 0; k < 15; ++k) {
      accA |= hfl[r0 + k][wcp];
      accB |= hfl[r0 + 16 + k][wcp];
    }
    const unsigned crawA = sraw[r0 + R_][wcp + 2];
    const unsigned crawB = sraw[r0 + 16 + R_][wcp + 2];
    const float cA0[4] = {pA0.x, pA0.y, pA0.z, pA0.w};
    const float cA1[4] = {pA1.x, pA1.y, pA1.z, pA1.w};
    const float cB0[4] = {pB0.x, pB0.y, pB0.z, pB0.w};
    const float cB1[4] = {pB1.x, pB1.y, pB1.z, pB1.w};
#pragma unroll
    for (int j = 0; j < 4; ++j) {
      const unsigned fA = (accA >> (8 * j)) & 0xFFu;
      const unsigned lA = (crawA >> (8 * j)) & 0xFFu;
      const bool okA = (fA == 3u) && (lA != 255u);
      lsum += okA ? (double)(lA ? cA1[j] : cA0[j]) : 0.0;
      lcnt += okA;
      const unsigned fB = (accB >> (8 * j)) & 0xFFu;
      const unsigned lB = (crawB >> (8 * j)) & 0xFFu;
      const bool okB = (fB == 3u) && (lB != 255u);
      lsum += okB ? (double)(lB ? cB1[j] : cB0[j]) : 0.0;
      lcnt += okB;
    }
  }

  // ---- block reduction -> ONE double2 store per block (no atomics) ----
#pragma unroll
  for (int off = 32; off > 0; off >>= 1) {
    lsum += __shfl_down(lsum, off, 64);
    lcnt += __shfl_down(lcnt, off, 64);
  }
  const int wave = tid >> 6;
  if ((tid & 63) == 0) { red_s[wave] = lsum; red_c[wave] = lcnt; }
  __syncthreads();
  if (tid == 0) {
    const double s = red_s[0] + red_s[1] + red_s[2] + red_s[3];
    const double c = (double)(red_c[0] + red_c[1] + red_c[2] + red_c[3]);
    const int bid = (blockIdx.z * GY + blockIdx.y) * GX + blockIdx.x;
    partials[bid] = make_double2(s, c);
  }
}

extern "C" __global__ __launch_bounds__(1024)
void boundary_loss_final(const double2* __restrict__ partials,
                         float* __restrict__ out)
{
  __shared__ double red_s[16];
  __shared__ double red_c[16];
  const int tid = threadIdx.x;
  double s = 0.0, c = 0.0;
  for (int i = tid; i < NBLK; i += 1024) {
    const double2 p = partials[i];
    s += p.x;
    c += p.y;
  }
#pragma unroll
  for (int off = 32; off > 0; off >>= 1) {
    s += __shfl_down(s, off, 64);
    c += __shfl_down(c, off, 64);
  }
  const int wave = tid >> 6;
  if ((tid & 63) == 0) { red_s[wave] = s; red_c[wave] = c; }
  __syncthreads();
  if (tid == 0) {
    double ts = 0.0, tc = 0.0;
#pragma unroll
    for (int i = 0; i < 16; ++i) { ts += red_s[i]; tc += red_c[i]; }
    if (tc < 1.0) tc = 1.0;
    out[0] = (float)(-ts / tc);
  }
}

extern "C" void kernel_launch(void* const* d_in, const int* in_sizes, int n_in,
                              void* d_out, int out_size, void* d_ws, size_t ws_size,
                              hipStream_t stream)
{
  const float* logits = (const float*)d_in[0];
  const int* labels = (const int*)d_in[1];
  float* out = (float*)d_out;
  double2* partials = (double2*)d_ws;  // NBLK*16 B = 107,520 B; every slot
                                       // written by main -> no init needed.

  dim3 grid(GX, GY, B_);
  boundary_loss_main<<<grid, 256, 0, stream>>>(logits, labels, partials);
  boundary_loss_final<<<1, 1024, 0, stream>>>(partials, out);
}